// Round 2
// baseline (435.272 us; speedup 1.0000x reference)
//
#include <hip/hip_runtime.h>
#include <hip/hip_bf16.h>

// SmoothnessConstraint: out[b,0,:]=x[b,0,:]; out[b,t,:]=out[b,t-1,:]+clip(x[b,t,:]-x[b,t-1,:],-0.5,0.5)
// B=4096, T=256, A=64, fp32.
//
// Key insight: clipped diffs d[t]=clip(x[t]-x[t-1]) are independent of the scan
// state, so this is a plain prefix sum over T -> parallelize over T, not just (b,a).
// One block per b. 256 threads = 16 a4-groups (float4 over A) x 16 T-segments of
// 16 steps. Each thread: 16 independent float4 loads (256 B in flight/thread),
// local clipped-diff prefix in registers, segment totals through LDS, add
// x[b,0,:] + prior-segment offset, 16 float4 stores. 4096 blocks -> deep
// oversubscription; memory-latency hiding comes from TLP + 16-deep load batch.

__device__ __forceinline__ float clip05(float d) {
    return fminf(fmaxf(d, -0.5f), 0.5f);
}

__global__ __launch_bounds__(256) void smooth_scan(
    const float* __restrict__ in, float* __restrict__ out) {
    constexpr int T    = 256;
    constexpr int A4   = 16;   // A/4 float4 per timestep
    constexpr int SEG  = 16;   // timesteps per thread
    constexpr int NSEG = 16;   // T / SEG

    __shared__ float4 lds_x0[A4];          // raw x[b,0,a4]
    __shared__ float4 lds_tot[NSEG][A4];   // per-segment clipped-diff totals

    const int b   = blockIdx.x;
    const int a4  = threadIdx.x & (A4 - 1);
    const int seg = threadIdx.x >> 4;

    const size_t base = (size_t)b * T * A4 + (size_t)seg * SEG * A4 + a4;
    const float4* __restrict__ ip = (const float4*)in + base;
    float4*       __restrict__ op = (float4*)out + base;

    // Batch-load this thread's 16 timesteps (independent -> all in flight).
    float4 v[SEG];
#pragma unroll
    for (int i = 0; i < SEG; ++i) v[i] = ip[i * A4];

    // Element preceding this segment (raw). For seg==0, prev=v[0] makes d[0]=0,
    // which is exactly what out[0]=x[0] needs once x0 is added as the offset.
    float4 prev = (seg != 0) ? ip[-A4] : v[0];

    if (seg == 0) lds_x0[a4] = v[0];   // publish raw x[b,0,a4] before overwrite

    // In-place local inclusive prefix of clipped diffs.
    float4 run = make_float4(0.f, 0.f, 0.f, 0.f);
#pragma unroll
    for (int i = 0; i < SEG; ++i) {
        const float4 cur = v[i];
        run.x += clip05(cur.x - prev.x);
        run.y += clip05(cur.y - prev.y);
        run.z += clip05(cur.z - prev.z);
        run.w += clip05(cur.w - prev.w);
        prev = cur;
        v[i] = run;
    }

    lds_tot[seg][a4] = run;   // segment total
    __syncthreads();

    // Offset = x[b,0,a4] + sum of totals of all earlier segments.
    float4 off = lds_x0[a4];
    for (int s = 0; s < seg; ++s) {
        const float4 t = lds_tot[s][a4];
        off.x += t.x; off.y += t.y; off.z += t.z; off.w += t.w;
    }

#pragma unroll
    for (int i = 0; i < SEG; ++i) {
        const float4 r = v[i];
        op[i * A4] = make_float4(off.x + r.x, off.y + r.y, off.z + r.z, off.w + r.w);
    }
}

extern "C" void kernel_launch(void* const* d_in, const int* in_sizes, int n_in,
                              void* d_out, int out_size, void* d_ws, size_t ws_size,
                              hipStream_t stream) {
    const float* in = (const float*)d_in[0];
    float* out = (float*)d_out;

    constexpr int B = 4096;
    smooth_scan<<<B, 256, 0, stream>>>(in, out);
}